// Round 10
// baseline (335.727 us; speedup 1.0000x reference)
//
#include <hip/hip_runtime.h>
#include <stdint.h>

#define NBINS 256
#define HW    (512 * 512)
#define NIMG  64
#define MMB   64   // K1/K4 blocks per image (4 tiles each)
#define HB    32   // K2 blocks per image (8 tiles each)
#define RB 0
#define GB 1032
#define BB 2064
#define STW 3096   // SoA staging words (12.4 KB)
#define FINV 0.00390625  // 2^-8, exact

// f64 grayscale, exact op order verified bit-exact vs np reference (rounds 3-7):
__device__ __forceinline__ double gray_of(float r, float g, float b) {
    return fma((double)b, (double)0.1140f,
           fma((double)g, (double)0.5870f,
               (double)r * (double)0.2989f));
}

// Stage one 1024-px tile (768 float4, fully lane-coalesced loads) into SoA LDS.
__device__ __forceinline__ void stage3(const float4* __restrict__ xv, int64_t tile4,
                                       float* __restrict__ st, int tid) {
    #pragma unroll
    for (int k = 0; k < 3; ++k) {
        const int q = k * 256 + tid;
        const float4 v = xv[tile4 + q];
        const int f0 = q * 4;
        int p = (int)(((unsigned)f0 * 21846u) >> 16);  // f0/3
        int c = f0 - 3 * p;                            // f0%3
        const float e[4] = {v.x, v.y, v.z, v.w};
        #pragma unroll
        for (int j = 0; j < 4; ++j) {
            const int base = (c == 0) ? RB : ((c == 1) ? GB : BB);
            st[base + p] = e[j];
            if (++c == 3) { c = 0; ++p; }
        }
    }
}

__device__ __forceinline__ int bin_of(double g, double mn, double s) {
    int id = (int)__dmul_rn(__dsub_rn(g, mn), s);  // trunc = astype(int32)
    return id < 0 ? 0 : (id > 255 ? 255 : id);
}

// K1: 64 blocks/img x 4 tiles (2 pairs); min/max partials + paired fid emit.
// fid = trunc(g*256.0): power-of-two scale is EXACT in f64 ->
// g in [fid/256,(fid+1)/256) with exact endpoints (round-7 proof, absmax 0).
__global__ __launch_bounds__(256) void k_minmax(const float* __restrict__ x,
        double* __restrict__ mm_part, ulonglong2* __restrict__ fidq,
        unsigned* __restrict__ cnt) {
    __shared__ float st[STW];
    __shared__ double smn[4], smx[4];
    const int tid = threadIdx.x;
    const int img = blockIdx.x >> 6;
    const int blk = blockIdx.x & 63;
    if (blk == 0 && tid < NIMG && blockIdx.x == (unsigned)(img << 6))
        if (tid == 0) cnt[img] = 0u;   // K2's last-block counter; K1 fully precedes K2
    const int64_t img4 = (int64_t)img * (HW * 3 / 4);
    const float4* xv = (const float4*)x;
    double mn = 1e300, mx = -1e300;
    unsigned long long fidA = 0;
    for (int it = 0; it < 4; ++it) {
        const int tl = blk * 4 + it;
        stage3(xv, img4 + (int64_t)tl * 768, st, tid);
        __syncthreads();
        const float4 R = *(const float4*)&st[RB + 4 * tid];
        const float4 G = *(const float4*)&st[GB + 4 * tid];
        const float4 B = *(const float4*)&st[BB + 4 * tid];
        const double g0 = gray_of(R.x, G.x, B.x), g1 = gray_of(R.y, G.y, B.y),
                     g2 = gray_of(R.z, G.z, B.z), g3 = gray_of(R.w, G.w, B.w);
        mn = fmin(mn, fmin(fmin(g0, g1), fmin(g2, g3)));
        mx = fmax(mx, fmax(fmax(g0, g1), fmax(g2, g3)));
        const unsigned long long pk =
              ((unsigned long long)(unsigned)(g0 * 256.0))
            | ((unsigned long long)(unsigned)(g1 * 256.0) << 16)
            | ((unsigned long long)(unsigned)(g2 * 256.0) << 32)
            | ((unsigned long long)(unsigned)(g3 * 256.0) << 48);
        if ((it & 1) == 0) fidA = pk;
        else {  // 16 B/lane coalesced paired store
            ulonglong2 v; v.x = fidA; v.y = pk;
            fidq[img * (HW / 8) + (blk * 2 + (it >> 1)) * 256 + tid] = v;
        }
        __syncthreads();
    }
    #pragma unroll
    for (int off = 32; off; off >>= 1) {
        mn = fmin(mn, __shfl_xor(mn, off));
        mx = fmax(mx, __shfl_xor(mx, off));
    }
    if ((tid & 63) == 0) { smn[tid >> 6] = mn; smx[tid >> 6] = mx; }
    __syncthreads();
    if (tid == 0) {
        mn = fmin(fmin(smn[0], smn[1]), fmin(smn[2], smn[3]));
        mx = fmax(fmax(smx[0], smx[1]), fmax(smx[2], smx[3]));
        mm_part[(img * MMB + blk) * 2 + 0] = mn;
        mm_part[(img * MMB + blk) * 2 + 1] = mx;
    }
}

// wave-0 reduce of the 64 min/max partials (exact; order-insensitive)
__device__ __forceinline__ void mm_reduce(const double* __restrict__ mm_part, int img,
                                          int tid, double* __restrict__ sdm) {
    if (tid < 64) {
        double mn = mm_part[(img * MMB + tid) * 2 + 0];
        double mx = mm_part[(img * MMB + tid) * 2 + 1];
        #pragma unroll
        for (int off = 32; off; off >>= 1) {
            mn = fmin(mn, __shfl_xor(mn, off));
            mx = fmax(mx, __shfl_xor(mx, off));
        }
        if (tid == 0) { sdm[0] = mn; sdm[1] = mx; }
    }
}

// K2: 32 blocks/img x 8 tiles (4 pairs): histogram partials from fid bracket;
// the LAST finishing block per image fuses the bit-exact f64 Otsu -> thr.
__global__ __launch_bounds__(256) void k_hist(const ulonglong2* __restrict__ fidq,
        const float* __restrict__ x, const double* __restrict__ mm_part,
        unsigned* __restrict__ hist_part, unsigned* __restrict__ cnt,
        double* __restrict__ thr) {
    __shared__ unsigned lh[NBINS];
    __shared__ double sdm[2];
    __shared__ double h[NBINS], w2s[NBINS], m2s[NBINS], vv[NBINS];
    __shared__ unsigned sdone;
    const int tid = threadIdx.x;
    const int img = blockIdx.x >> 5;
    const int blk = blockIdx.x & 31;
    lh[tid] = 0u;
    mm_reduce(mm_part, img, tid, sdm);
    __syncthreads();
    const double mn = sdm[0];
    const double s  = 256.0 / fmax(__dsub_rn(sdm[1], mn), 1e-12);
    for (int pr = 0; pr < 4; ++pr) {
        const int tp = blk * 4 + pr;            // tile pair: tiles 2tp, 2tp+1
        const ulonglong2 pv = fidq[img * (HW / 8) + tp * 256 + tid];
        #pragma unroll
        for (int half = 0; half < 2; ++half) {
            const unsigned long long pk = half ? pv.y : pv.x;
            const int tl = tp * 2 + half;
            #pragma unroll
            for (int j = 0; j < 4; ++j) {
                const unsigned f = (unsigned)(pk >> (16 * j)) & 0xFFFFu;
                const int clo = bin_of((double)f * FINV, mn, s);
                const int chi = bin_of((double)(f + 1) * FINV, mn, s);
                int id;
                if (clo == chi) id = clo;
                else {  // boundary fine-bin (~0.4%): recompute exact gray
                    const int64_t p = (int64_t)img * HW + (int64_t)tl * 1024 + 4 * tid + j;
                    id = bin_of(gray_of(x[3 * p], x[3 * p + 1], x[3 * p + 2]), mn, s);
                }
                atomicAdd(&lh[id], 1u);
            }
        }
    }
    __syncthreads();
    hist_part[(img * HB + blk) * NBINS + tid] = lh[tid];
    __threadfence();                          // release my partial device-wide
    __syncthreads();                          // order all threads' fences
    if (tid == 0)
        sdone = __hip_atomic_fetch_add(&cnt[img], 1u, __ATOMIC_ACQ_REL,
                                       __HIP_MEMORY_SCOPE_AGENT);
    __syncthreads();
    if (sdone != HB - 1) return;              // only the last block continues
    __threadfence();                          // acquire others' partials
    unsigned hu = 0;
    for (int b = 0; b < HB; ++b) hu += hist_part[(img * HB + b) * NBINS + tid];  // exact int
    h[tid] = (double)hu;
    __syncthreads();
    const double rng  = fmax(__dsub_rn(sdm[1], mn), 1e-12);
    const double step = rng / 256.0;
    // per-thread ordered partial sums == numpy serial cumsum, bit-exact (r4-7)
    double w1 = 0.0, hc1 = 0.0;
    for (int j = 0; j <= tid; ++j) {
        const double c = __dadd_rn(mn, __dmul_rn((double)j + 0.5, step));
        w1  = __dadd_rn(w1, h[j]);
        hc1 = __dadd_rn(hc1, __dmul_rn(h[j], c));
    }
    const double m1 = hc1 / fmax(w1, 1e-12);
    double w2 = 0.0, hc2 = 0.0;
    for (int j = NBINS - 1; j >= tid; --j) {
        const double c = __dadd_rn(mn, __dmul_rn((double)j + 0.5, step));
        w2  = __dadd_rn(w2, h[j]);
        hc2 = __dadd_rn(hc2, __dmul_rn(h[j], c));
    }
    w2s[tid] = w2;
    m2s[tid] = hc2 / fmax(w2, 1e-12);
    __syncthreads();
    if (tid < NBINS - 1) {
        const double d = __dsub_rn(m1, m2s[tid + 1]);
        vv[tid] = __dmul_rn(__dmul_rn(w1, w2s[tid + 1]), __dmul_rn(d, d));
    }
    __syncthreads();
    if (tid == 0) {
        double best = -1.0; int bi = 0;
        for (int i = 0; i < NBINS - 1; ++i)
            if (vv[i] > best) { best = vv[i]; bi = i; }   // first-occurrence argmax
        thr[img] = __dadd_rn(mn, __dmul_rn((double)bi + 0.5, step));
    }
}

// K4: 64 blocks/img x 2 tile-pairs: binarize from fid bracket + LDS-broadcast
// coalesced output (16 B/lane stores; round-5 proved 48 B/lane is ~6x slower).
__global__ __launch_bounds__(256) void k_binarize(const ulonglong2* __restrict__ fidq,
        const float* __restrict__ x, const double* __restrict__ thr,
        float* __restrict__ out) {
    __shared__ float bst[2048];
    const int tid = threadIdx.x;
    const int img = blockIdx.x >> 6;
    const int blk = blockIdx.x & 63;
    const double T = thr[img];
    const int64_t img4 = (int64_t)img * (HW * 3 / 4);
    float4* ov = (float4*)out;
    for (int pr = 0; pr < 2; ++pr) {
        const int tp = blk * 2 + pr;            // tiles 2tp, 2tp+1
        const ulonglong2 pv = fidq[img * (HW / 8) + tp * 256 + tid];
        #pragma unroll
        for (int half = 0; half < 2; ++half) {
            const unsigned long long pk = half ? pv.y : pv.x;
            const int tl = tp * 2 + half;
            #pragma unroll
            for (int j = 0; j < 4; ++j) {
                const unsigned f = (unsigned)(pk >> (16 * j)) & 0xFFFFu;
                const double glo = (double)f * FINV;          // exact, g >= glo
                const double ghi = (double)(f + 1) * FINV;    // exact, g <  ghi
                float r;
                if (glo > T)       r = 255.f;
                else if (ghi <= T) r = 0.f;
                else {  // threshold inside fine bin (rare): recompute exact gray
                    const int64_t p = (int64_t)img * HW + (int64_t)tl * 1024 + 4 * tid + j;
                    const double g = gray_of(x[3 * p], x[3 * p + 1], x[3 * p + 2]);
                    r = (g > T) ? 255.f : 0.f;
                }
                bst[half * 1024 + 4 * tid + j] = r;
            }
        }
        __syncthreads();
        const int64_t ob4 = img4 + (int64_t)tp * 1536;
        #pragma unroll
        for (int k = 0; k < 6; ++k) {
            const int q  = k * 256 + tid;                                // [0,1536)
            const int p0 = (int)(((unsigned)(q * 4) * 21846u) >> 16);    // (4q)/3
            const int m  = q - 3 * (int)(((unsigned)q * 21846u) >> 16);  // q%3
            const float lo = bst[p0];
            const float hi = bst[p0 + 1 < 2048 ? p0 + 1 : 2047];
            float4 o;
            o.x = lo;
            o.y = (m + 1 >= 3) ? hi : lo;
            o.z = (m + 2 >= 3) ? hi : lo;
            o.w = (m + 3 >= 3) ? hi : lo;
            ov[ob4 + q] = o;   // 16 B/lane, fully coalesced
        }
        __syncthreads();
    }
}

extern "C" void kernel_launch(void* const* d_in, const int* in_sizes, int n_in,
                              void* d_out, int out_size, void* d_ws, size_t ws_size,
                              hipStream_t stream) {
    const float* x = (const float*)d_in[0];
    float* out = (float*)d_out;
    uint8_t* ws = (uint8_t*)d_ws;

    // ws: [0,512) thr f64 | [512,768) cnt u32 | [1024,66560) mm_part f64 |
    //     [66560,+2MiB) hist_part u32 | [4MiB,+33.5MiB) fidq ulonglong2
    double*     thr       = (double*)(ws);
    unsigned*   cnt       = (unsigned*)(ws + 512);
    double*     mm_part   = (double*)(ws + 1024);
    unsigned*   hist_part = (unsigned*)(ws + 66560);
    ulonglong2* fidq      = (ulonglong2*)(ws + 4194304);

    k_minmax<<<NIMG * MMB, 256, 0, stream>>>(x, mm_part, fidq, cnt);
    k_hist<<<NIMG * HB, 256, 0, stream>>>(fidq, x, mm_part, hist_part, cnt, thr);
    k_binarize<<<NIMG * MMB, 256, 0, stream>>>(fidq, x, thr, out);
}

// Round 11
// 137.390 us; speedup vs baseline: 2.4436x; 2.4436x over previous
//
#include <hip/hip_runtime.h>
#include <stdint.h>

#define NBINS 256
#define HW    (512 * 512)
#define NIMG  64
#define MMB   64   // K1/K4 blocks per image (4 tiles each)
#define HB    32   // K2 blocks per image (8 tiles each)
#define STW   3072 // AoS tile words (1024 px * 3 ch) = 12 KB
#define FINV  0.00390625  // 2^-8, exact

// f64 grayscale, exact op order verified bit-exact vs np reference (rounds 3-7):
__device__ __forceinline__ double gray_of(float r, float g, float b) {
    return fma((double)b, (double)0.1140f,
           fma((double)g, (double)0.5870f,
               (double)r * (double)0.2989f));
}

__device__ __forceinline__ int bin_of(double g, double mn, double s) {
    int id = (int)__dmul_rn(__dsub_rn(g, mn), s);  // trunc = astype(int32)
    return id < 0 ? 0 : (id > 255 ? 255 : id);
}

// K1: 64 blocks/img x 4 tiles; min/max partials + u16 fine-index (fid) emit.
// Staging: LINEAR AoS — 3 coalesced float4 LDS writes/thread; per-pixel reads
// at word 3*tid+768*j+c: gcd(3,32)=1 -> 2 lanes/bank = conflict-free (m136).
// fid = trunc(g*256.0): power-of-two scale is EXACT in f64 ->
// g in [fid/256,(fid+1)/256) with exact endpoints (round-7 proof, absmax 0).
// Pixel mapping (consistent with K2/K4): px = tl*1024 + tid + 256*j.
__global__ __launch_bounds__(256) void k_minmax(const float* __restrict__ x,
        double* __restrict__ mm_part, unsigned long long* __restrict__ fid4) {
    __shared__ float st[STW];
    __shared__ double smn[4], smx[4];
    const int tid = threadIdx.x;
    const int img = blockIdx.x >> 6;
    const int blk = blockIdx.x & 63;
    const int64_t img4 = (int64_t)img * (HW * 3 / 4);
    const float4* xv = (const float4*)x;
    double mn = 1e300, mx = -1e300;
    for (int it = 0; it < 4; ++it) {
        const int tl = blk * 4 + it;
        const int64_t t4 = img4 + (int64_t)tl * 768;
        #pragma unroll
        for (int k = 0; k < 3; ++k)
            *(float4*)&st[(k * 256 + tid) * 4] = xv[t4 + k * 256 + tid];
        __syncthreads();
        unsigned long long pk = 0;
        #pragma unroll
        for (int j = 0; j < 4; ++j) {
            const int w = 3 * tid + 768 * j;
            const double g = gray_of(st[w], st[w + 1], st[w + 2]);
            mn = fmin(mn, g);
            mx = fmax(mx, g);
            pk |= (unsigned long long)(unsigned)(g * 256.0) << (16 * j);
        }
        fid4[img * (HW / 4) + tl * 256 + tid] = pk;
        __syncthreads();   // st reusable next tile
    }
    #pragma unroll
    for (int off = 32; off; off >>= 1) {
        mn = fmin(mn, __shfl_xor(mn, off));
        mx = fmax(mx, __shfl_xor(mx, off));
    }
    if ((tid & 63) == 0) { smn[tid >> 6] = mn; smx[tid >> 6] = mx; }
    __syncthreads();
    if (tid == 0) {
        mn = fmin(fmin(smn[0], smn[1]), fmin(smn[2], smn[3]));
        mx = fmax(fmax(smx[0], smx[1]), fmax(smx[2], smx[3]));
        mm_part[(img * MMB + blk) * 2 + 0] = mn;
        mm_part[(img * MMB + blk) * 2 + 1] = mx;
    }
}

// wave-0 reduce of the 64 min/max partials (exact; order-insensitive)
__device__ __forceinline__ void mm_reduce(const double* __restrict__ mm_part, int img,
                                          int tid, double* __restrict__ sdm) {
    if (tid < 64) {
        double mn = mm_part[(img * MMB + tid) * 2 + 0];
        double mx = mm_part[(img * MMB + tid) * 2 + 1];
        #pragma unroll
        for (int off = 32; off; off >>= 1) {
            mn = fmin(mn, __shfl_xor(mn, off));
            mx = fmax(mx, __shfl_xor(mx, off));
        }
        if (tid == 0) { sdm[0] = mn; sdm[1] = mx; }
    }
}

// K2: 32 blocks/img x 8 tiles: histogram partials from fid (33 MB, L3-resident).
// Monotone bracket: same coarse bin for both exact endpoints -> exact;
// else (~0.4%) gather-recompute exact gray.
__global__ __launch_bounds__(256) void k_hist(const unsigned long long* __restrict__ fid4,
        const float* __restrict__ x, const double* __restrict__ mm_part,
        unsigned* __restrict__ hist_part) {
    __shared__ unsigned lh[NBINS];
    __shared__ double sdm[2];
    const int tid = threadIdx.x;
    const int img = blockIdx.x >> 5;
    const int blk = blockIdx.x & 31;
    lh[tid] = 0u;
    mm_reduce(mm_part, img, tid, sdm);
    __syncthreads();
    const double mn = sdm[0];
    const double s  = 256.0 / fmax(__dsub_rn(sdm[1], mn), 1e-12);
    for (int it = 0; it < 8; ++it) {
        const int tl = blk * 8 + it;
        const unsigned long long pk = fid4[img * (HW / 4) + tl * 256 + tid];
        #pragma unroll
        for (int j = 0; j < 4; ++j) {
            const unsigned f = (unsigned)(pk >> (16 * j)) & 0xFFFFu;
            const int clo = bin_of((double)f * FINV, mn, s);
            const int chi = bin_of((double)(f + 1) * FINV, mn, s);
            int id;
            if (clo == chi) id = clo;
            else {  // boundary fine-bin: recompute exact gray (rare)
                const int64_t p = (int64_t)img * HW + (int64_t)tl * 1024 + tid + 256 * j;
                id = bin_of(gray_of(x[3 * p], x[3 * p + 1], x[3 * p + 2]), mn, s);
            }
            atomicAdd(&lh[id], 1u);
        }
    }
    __syncthreads();
    hist_part[(img * HB + blk) * NBINS + tid] = lh[tid];
}

// K3: one 256-thread block per image; integer partial-sum + bit-exact f64 Otsu
__global__ void k_otsu(const unsigned* __restrict__ hist_part,
                       const double* __restrict__ mm_part,
                       double* __restrict__ thr) {
    __shared__ double h[NBINS], w2s[NBINS], m2s[NBINS], vv[NBINS];
    __shared__ double sdm[2];
    const int img = blockIdx.x, t = threadIdx.x;
    mm_reduce(mm_part, img, t, sdm);
    unsigned hu = 0;
    for (int b = 0; b < HB; ++b) hu += hist_part[(img * HB + b) * NBINS + t];  // exact int
    h[t] = (double)hu;
    __syncthreads();
    const double mn   = sdm[0];
    const double rng  = fmax(__dsub_rn(sdm[1], mn), 1e-12);
    const double step = rng / 256.0;
    // per-thread ordered partial sums == numpy serial cumsum, bit-exact (r4-7)
    double w1 = 0.0, hc1 = 0.0;
    for (int j = 0; j <= t; ++j) {
        const double c = __dadd_rn(mn, __dmul_rn((double)j + 0.5, step));
        w1  = __dadd_rn(w1, h[j]);
        hc1 = __dadd_rn(hc1, __dmul_rn(h[j], c));
    }
    const double m1 = hc1 / fmax(w1, 1e-12);
    double w2 = 0.0, hc2 = 0.0;
    for (int j = NBINS - 1; j >= t; --j) {
        const double c = __dadd_rn(mn, __dmul_rn((double)j + 0.5, step));
        w2  = __dadd_rn(w2, h[j]);
        hc2 = __dadd_rn(hc2, __dmul_rn(h[j], c));
    }
    w2s[t] = w2;
    m2s[t] = hc2 / fmax(w2, 1e-12);
    __syncthreads();
    if (t < NBINS - 1) {
        const double d = __dsub_rn(m1, m2s[t + 1]);
        vv[t] = __dmul_rn(__dmul_rn(w1, w2s[t + 1]), __dmul_rn(d, d));
    }
    __syncthreads();
    if (t == 0) {
        double best = -1.0; int bi = 0;
        for (int i = 0; i < NBINS - 1; ++i)
            if (vv[i] > best) { best = vv[i]; bi = i; }   // first-occurrence argmax
        thr[img] = __dadd_rn(mn, __dmul_rn((double)bi + 0.5, step));
    }
}

// K4: 64 blocks/img x 4 tiles: binarize from fid bracket + LDS-broadcast output
// (coalesced 16 B/lane stores; round 5 proved 48 B/lane stores are ~6x slower).
__global__ __launch_bounds__(256) void k_binarize(const unsigned long long* __restrict__ fid4,
        const float* __restrict__ x, const double* __restrict__ thr,
        float* __restrict__ out) {
    __shared__ float bst[1024];
    const int tid = threadIdx.x;
    const int img = blockIdx.x >> 6;
    const int blk = blockIdx.x & 63;
    const double T = thr[img];
    const int64_t img4 = (int64_t)img * (HW * 3 / 4);
    float4* ov = (float4*)out;
    for (int it = 0; it < 4; ++it) {
        const int tl = blk * 4 + it;
        const unsigned long long pk = fid4[img * (HW / 4) + tl * 256 + tid];
        #pragma unroll
        for (int j = 0; j < 4; ++j) {
            const unsigned f = (unsigned)(pk >> (16 * j)) & 0xFFFFu;
            const double glo = (double)f * FINV;          // exact, g >= glo
            const double ghi = (double)(f + 1) * FINV;    // exact, g <  ghi
            float r;
            if (glo > T)       r = 255.f;
            else if (ghi <= T) r = 0.f;
            else {  // threshold inside fine bin (rare): recompute exact gray
                const int64_t p = (int64_t)img * HW + (int64_t)tl * 1024 + tid + 256 * j;
                const double g = gray_of(x[3 * p], x[3 * p + 1], x[3 * p + 2]);
                r = (g > T) ? 255.f : 0.f;
            }
            bst[tid + 256 * j] = r;   // pixel-indexed; stride-1 per j, conflict-free
        }
        __syncthreads();
        const int64_t ob4 = img4 + (int64_t)tl * 768;
        #pragma unroll
        for (int k = 0; k < 3; ++k) {
            const int q  = k * 256 + tid;
            const int p0 = (int)(((unsigned)(q * 4) * 21846u) >> 16);   // (4q)/3
            const int m  = q - 3 * (int)(((unsigned)q * 21846u) >> 16); // q%3
            const float lo = bst[p0];
            const float hi = bst[p0 + 1 < 1024 ? p0 + 1 : 1023];
            float4 o;
            o.x = lo;
            o.y = (m + 1 >= 3) ? hi : lo;
            o.z = (m + 2 >= 3) ? hi : lo;
            o.w = (m + 3 >= 3) ? hi : lo;
            ov[ob4 + q] = o;   // 16 B/lane, fully coalesced
        }
        __syncthreads();   // bst reusable next tile
    }
}

extern "C" void kernel_launch(void* const* d_in, const int* in_sizes, int n_in,
                              void* d_out, int out_size, void* d_ws, size_t ws_size,
                              hipStream_t stream) {
    const float* x = (const float*)d_in[0];
    float* out = (float*)d_out;
    uint8_t* ws = (uint8_t*)d_ws;

    // ws: [0,512) thr f64 | [1024,66560) mm_part f64 | [66560,+2MiB) hist_part u32 |
    //     [2163712, +32MiB) fid4 u16-packed-x4
    double*             thr       = (double*)(ws);
    double*             mm_part   = (double*)(ws + 1024);
    unsigned*           hist_part = (unsigned*)(ws + 66560);
    unsigned long long* fid4      = (unsigned long long*)(ws + 2163712);

    k_minmax<<<NIMG * MMB, 256, 0, stream>>>(x, mm_part, fid4);
    k_hist<<<NIMG * HB, 256, 0, stream>>>(fid4, x, mm_part, hist_part);
    k_otsu<<<NIMG, 256, 0, stream>>>(hist_part, mm_part, thr);
    k_binarize<<<NIMG * MMB, 256, 0, stream>>>(fid4, x, thr, out);
}

// Round 13
// 122.890 us; speedup vs baseline: 2.7319x; 1.1180x over previous
//
#include <hip/hip_runtime.h>
#include <stdint.h>

#define NBINS 256
#define HW    (512 * 512)
#define NIMG  64
#define MMB   64   // K1/K4 blocks per image (4 tiles each)
#define HB    32   // K2 blocks per image (8 tiles each)
#define STW   3072 // AoS tile words (1024 px * 3 ch) = 12 KB
#define FINV  0.00390625  // 2^-8, exact

typedef float nfloat4 __attribute__((ext_vector_type(4)));  // native vec for nontemporal

// f64 grayscale, exact op order verified bit-exact vs np reference (rounds 3-11):
__device__ __forceinline__ double gray_of(float r, float g, float b) {
    return fma((double)b, (double)0.1140f,
           fma((double)g, (double)0.5870f,
               (double)r * (double)0.2989f));
}

__device__ __forceinline__ int bin_of(double g, double mn, double s) {
    int id = (int)__dmul_rn(__dsub_rn(g, mn), s);  // trunc = astype(int32)
    return id < 0 ? 0 : (id > 255 ? 255 : id);
}

// K1: 64 blocks/img x 4 tiles; min/max partials + u16 fine-index (fid) emit.
// Staging: linear AoS, NONTEMPORAL loads (x is streamed once; don't allocate).
// fid = trunc(g*256.0): power-of-two scale is EXACT in f64 ->
// g in [fid/256,(fid+1)/256) with exact endpoints (round-7 proof, absmax 0).
// Pixel mapping (consistent with K2/K4): px = tl*1024 + tid + 256*j.
__global__ __launch_bounds__(256) void k_minmax(const float* __restrict__ x,
        double* __restrict__ mm_part, unsigned long long* __restrict__ fid4) {
    __shared__ float st[STW];
    __shared__ double smn[4], smx[4];
    const int tid = threadIdx.x;
    const int img = blockIdx.x >> 6;
    const int blk = blockIdx.x & 63;
    const int64_t img4 = (int64_t)img * (HW * 3 / 4);
    const nfloat4* xv = (const nfloat4*)x;
    double mn = 1e300, mx = -1e300;
    for (int it = 0; it < 4; ++it) {
        const int tl = blk * 4 + it;
        const int64_t t4 = img4 + (int64_t)tl * 768;
        #pragma unroll
        for (int k = 0; k < 3; ++k)
            *(nfloat4*)&st[(k * 256 + tid) * 4] =
                __builtin_nontemporal_load(&xv[t4 + k * 256 + tid]);
        __syncthreads();
        unsigned long long pk = 0;
        #pragma unroll
        for (int j = 0; j < 4; ++j) {
            const int w = 3 * tid + 768 * j;
            const double g = gray_of(st[w], st[w + 1], st[w + 2]);
            mn = fmin(mn, g);
            mx = fmax(mx, g);
            pk |= (unsigned long long)(unsigned)(g * 256.0) << (16 * j);
        }
        fid4[img * (HW / 4) + tl * 256 + tid] = pk;
        __syncthreads();   // st reusable next tile
    }
    #pragma unroll
    for (int off = 32; off; off >>= 1) {
        mn = fmin(mn, __shfl_xor(mn, off));
        mx = fmax(mx, __shfl_xor(mx, off));
    }
    if ((tid & 63) == 0) { smn[tid >> 6] = mn; smx[tid >> 6] = mx; }
    __syncthreads();
    if (tid == 0) {
        mn = fmin(fmin(smn[0], smn[1]), fmin(smn[2], smn[3]));
        mx = fmax(fmax(smx[0], smx[1]), fmax(smx[2], smx[3]));
        mm_part[(img * MMB + blk) * 2 + 0] = mn;
        mm_part[(img * MMB + blk) * 2 + 1] = mx;
    }
}

// wave-0 reduce of the 64 min/max partials (exact; order-insensitive)
__device__ __forceinline__ void mm_reduce(const double* __restrict__ mm_part, int img,
                                          int tid, double* __restrict__ sdm) {
    if (tid < 64) {
        double mn = mm_part[(img * MMB + tid) * 2 + 0];
        double mx = mm_part[(img * MMB + tid) * 2 + 1];
        #pragma unroll
        for (int off = 32; off; off >>= 1) {
            mn = fmin(mn, __shfl_xor(mn, off));
            mx = fmax(mx, __shfl_xor(mx, off));
        }
        if (tid == 0) { sdm[0] = mn; sdm[1] = mx; }
    }
}

// K2: 32 blocks/img x 8 tiles: histogram partials from fid (33 MB, L3-resident).
// Monotone bracket: same coarse bin for both exact endpoints -> exact;
// else (~0.4%) gather-recompute exact gray.
__global__ __launch_bounds__(256) void k_hist(const unsigned long long* __restrict__ fid4,
        const float* __restrict__ x, const double* __restrict__ mm_part,
        unsigned* __restrict__ hist_part) {
    __shared__ unsigned lh[NBINS];
    __shared__ double sdm[2];
    const int tid = threadIdx.x;
    const int img = blockIdx.x >> 5;
    const int blk = blockIdx.x & 31;
    lh[tid] = 0u;
    mm_reduce(mm_part, img, tid, sdm);
    __syncthreads();
    const double mn = sdm[0];
    const double s  = 256.0 / fmax(__dsub_rn(sdm[1], mn), 1e-12);
    for (int it = 0; it < 8; ++it) {
        const int tl = blk * 8 + it;
        const unsigned long long pk = fid4[img * (HW / 4) + tl * 256 + tid];
        #pragma unroll
        for (int j = 0; j < 4; ++j) {
            const unsigned f = (unsigned)(pk >> (16 * j)) & 0xFFFFu;
            const int clo = bin_of((double)f * FINV, mn, s);
            const int chi = bin_of((double)(f + 1) * FINV, mn, s);
            int id;
            if (clo == chi) id = clo;
            else {  // boundary fine-bin: recompute exact gray (rare)
                const int64_t p = (int64_t)img * HW + (int64_t)tl * 1024 + tid + 256 * j;
                id = bin_of(gray_of(x[3 * p], x[3 * p + 1], x[3 * p + 2]), mn, s);
            }
            atomicAdd(&lh[id], 1u);
        }
    }
    __syncthreads();
    hist_part[(img * HB + blk) * NBINS + tid] = lh[tid];
}

// K3: one 256-thread block per image; integer partial-sum + bit-exact f64 Otsu
__global__ void k_otsu(const unsigned* __restrict__ hist_part,
                       const double* __restrict__ mm_part,
                       double* __restrict__ thr) {
    __shared__ double h[NBINS], w2s[NBINS], m2s[NBINS], vv[NBINS];
    __shared__ double sdm[2];
    const int img = blockIdx.x, t = threadIdx.x;
    mm_reduce(mm_part, img, t, sdm);
    unsigned hu = 0;
    for (int b = 0; b < HB; ++b) hu += hist_part[(img * HB + b) * NBINS + t];  // exact int
    h[t] = (double)hu;
    __syncthreads();
    const double mn   = sdm[0];
    const double rng  = fmax(__dsub_rn(sdm[1], mn), 1e-12);
    const double step = rng / 256.0;
    // per-thread ordered partial sums == numpy serial cumsum, bit-exact (r4-7)
    double w1 = 0.0, hc1 = 0.0;
    for (int j = 0; j <= t; ++j) {
        const double c = __dadd_rn(mn, __dmul_rn((double)j + 0.5, step));
        w1  = __dadd_rn(w1, h[j]);
        hc1 = __dadd_rn(hc1, __dmul_rn(h[j], c));
    }
    const double m1 = hc1 / fmax(w1, 1e-12);
    double w2 = 0.0, hc2 = 0.0;
    for (int j = NBINS - 1; j >= t; --j) {
        const double c = __dadd_rn(mn, __dmul_rn((double)j + 0.5, step));
        w2  = __dadd_rn(w2, h[j]);
        hc2 = __dadd_rn(hc2, __dmul_rn(h[j], c));
    }
    w2s[t] = w2;
    m2s[t] = hc2 / fmax(w2, 1e-12);
    __syncthreads();
    if (t < NBINS - 1) {
        const double d = __dsub_rn(m1, m2s[t + 1]);
        vv[t] = __dmul_rn(__dmul_rn(w1, w2s[t + 1]), __dmul_rn(d, d));
    }
    __syncthreads();
    if (t == 0) {
        double best = -1.0; int bi = 0;
        for (int i = 0; i < NBINS - 1; ++i)
            if (vv[i] > best) { best = vv[i]; bi = i; }   // first-occurrence argmax
        thr[img] = __dadd_rn(mn, __dmul_rn((double)bi + 0.5, step));
    }
}

// K4: 64 blocks/img x 4 tiles: binarize from fid bracket + LDS-broadcast output.
// Output: NONTEMPORAL 16 B/lane coalesced stores (out is never re-read;
// avoid L2/L3 write-allocate evicting the fid/x lines the gathers need).
__global__ __launch_bounds__(256) void k_binarize(const unsigned long long* __restrict__ fid4,
        const float* __restrict__ x, const double* __restrict__ thr,
        float* __restrict__ out) {
    __shared__ float bst[1024];
    const int tid = threadIdx.x;
    const int img = blockIdx.x >> 6;
    const int blk = blockIdx.x & 63;
    const double T = thr[img];
    const int64_t img4 = (int64_t)img * (HW * 3 / 4);
    nfloat4* ov = (nfloat4*)out;
    for (int it = 0; it < 4; ++it) {
        const int tl = blk * 4 + it;
        const unsigned long long pk = fid4[img * (HW / 4) + tl * 256 + tid];
        #pragma unroll
        for (int j = 0; j < 4; ++j) {
            const unsigned f = (unsigned)(pk >> (16 * j)) & 0xFFFFu;
            const double glo = (double)f * FINV;          // exact, g >= glo
            const double ghi = (double)(f + 1) * FINV;    // exact, g <  ghi
            float r;
            if (glo > T)       r = 255.f;
            else if (ghi <= T) r = 0.f;
            else {  // threshold inside fine bin (rare): recompute exact gray
                const int64_t p = (int64_t)img * HW + (int64_t)tl * 1024 + tid + 256 * j;
                const double g = gray_of(x[3 * p], x[3 * p + 1], x[3 * p + 2]);
                r = (g > T) ? 255.f : 0.f;
            }
            bst[tid + 256 * j] = r;   // pixel-indexed; stride-1 per j, conflict-free
        }
        __syncthreads();
        const int64_t ob4 = img4 + (int64_t)tl * 768;
        #pragma unroll
        for (int k = 0; k < 3; ++k) {
            const int q  = k * 256 + tid;
            const int p0 = (int)(((unsigned)(q * 4) * 21846u) >> 16);   // (4q)/3
            const int m  = q - 3 * (int)(((unsigned)q * 21846u) >> 16); // q%3
            const float lo = bst[p0];
            const float hi = bst[p0 + 1 < 1024 ? p0 + 1 : 1023];
            nfloat4 o;
            o.x = lo;
            o.y = (m + 1 >= 3) ? hi : lo;
            o.z = (m + 2 >= 3) ? hi : lo;
            o.w = (m + 3 >= 3) ? hi : lo;
            __builtin_nontemporal_store(o, &ov[ob4 + q]);   // 16 B/lane, coalesced
        }
        __syncthreads();   // bst reusable next tile
    }
}

extern "C" void kernel_launch(void* const* d_in, const int* in_sizes, int n_in,
                              void* d_out, int out_size, void* d_ws, size_t ws_size,
                              hipStream_t stream) {
    const float* x = (const float*)d_in[0];
    float* out = (float*)d_out;
    uint8_t* ws = (uint8_t*)d_ws;

    // ws: [0,512) thr f64 | [1024,66560) mm_part f64 | [66560,+2MiB) hist_part u32 |
    //     [2163712, +32MiB) fid4 u16-packed-x4
    double*             thr       = (double*)(ws);
    double*             mm_part   = (double*)(ws + 1024);
    unsigned*           hist_part = (unsigned*)(ws + 66560);
    unsigned long long* fid4      = (unsigned long long*)(ws + 2163712);

    k_minmax<<<NIMG * MMB, 256, 0, stream>>>(x, mm_part, fid4);
    k_hist<<<NIMG * HB, 256, 0, stream>>>(fid4, x, mm_part, hist_part);
    k_otsu<<<NIMG, 256, 0, stream>>>(hist_part, mm_part, thr);
    k_binarize<<<NIMG * MMB, 256, 0, stream>>>(fid4, x, thr, out);
}